// Round 6
// baseline (345.512 us; speedup 1.0000x reference)
//
#include <hip/hip_runtime.h>

// Problem constants: x [4, 64, 64, 128] fp32
constexpr int C       = 128;
constexpr int N       = 4096;
constexpr int BATCH   = 4;
constexpr int TOTROWS = BATCH * N;            // 16384
constexpr float SCALE = 0.08838834764831845f; // 1/sqrt(128)

constexpr int BK   = 64;     // keys per iteration
constexpr int PSTR = 72;     // P-tile LDS stride (bf16 elems): 144 B rows

typedef __attribute__((ext_vector_type(8))) short bf16x8;
typedef __attribute__((ext_vector_type(4))) float f32x4;

__device__ inline unsigned short f2bf(float f) {   // RNE float->bf16
    unsigned int u = __float_as_uint(f);
    return (unsigned short)((u + 0x7FFFu + ((u >> 16) & 1u)) >> 16);
}
__device__ inline unsigned int pack2bf(float a, float b) {
    return (unsigned int)f2bf(a) | ((unsigned int)f2bf(b) << 16);
}
__device__ inline float bf2f(unsigned short u) {
    return __uint_as_float((unsigned int)u << 16);
}

// ---------------------------------------------------------------------------
// wprep: 3 blocks. Coalesced W read -> LDS transpose -> coalesced Wt write.
// Wt[mat][o][i] = W[mat][i][o] (bf16, SCALE folded into mat 0), bias fp32.
// ---------------------------------------------------------------------------
__global__ __launch_bounds__(256)
void wprep_kernel(const float* __restrict__ Wq, const float* __restrict__ bq,
                  const float* __restrict__ Wk, const float* __restrict__ bk,
                  const float* __restrict__ Wv, const float* __restrict__ bv,
                  unsigned short* __restrict__ Wt,
                  float* __restrict__ bprep)
{
    constexpr int TS = 136;
    __shared__ __align__(16) unsigned short wl[128 * TS];
    const int tid = threadIdx.x;
    const int mat = blockIdx.x;
    const float* W = (mat == 0) ? Wq : (mat == 1) ? Wk : Wv;
    const float* b = (mat == 0) ? bq : (mat == 1) ? bk : bv;
    const float s  = (mat == 0) ? SCALE : 1.0f;

    #pragma unroll
    for (int g = 0; g < 16; ++g) {
        int idx = g * 256 + tid;
        int i = idx >> 5, c4 = (idx & 31) * 4;
        float4 a = *reinterpret_cast<const float4*>(&W[i * 128 + c4]);
        wl[(c4 + 0) * TS + i] = f2bf(a.x * s);
        wl[(c4 + 1) * TS + i] = f2bf(a.y * s);
        wl[(c4 + 2) * TS + i] = f2bf(a.z * s);
        wl[(c4 + 3) * TS + i] = f2bf(a.w * s);
    }
    __syncthreads();
    #pragma unroll
    for (int g = 0; g < 8; ++g) {
        int idx = g * 256 + tid;
        int o = idx >> 4, off = (idx & 15) * 8;
        *reinterpret_cast<uint4*>(&Wt[mat * 16384 + o * 128 + off]) =
            *reinterpret_cast<const uint4*>(&wl[o * TS + off]);
    }
    if (tid < 128) bprep[mat * 128 + tid] = b[tid] * s;
}

// ---------------------------------------------------------------------------
// Fused QKV GEMM: all three mats in one kernel, x read ONCE (fp32->bf16 in
// regs). grid 256 blocks, block 256 (4 waves), wave owns 16 rows.
// W fragments stream from L2 (96 KB, hot across all CUs).
// vt stored TILED: vt[b][n/64][c][n%64].
// ---------------------------------------------------------------------------
__global__ __launch_bounds__(256)
void qkv_kernel(const float* __restrict__ x,
                const unsigned short* __restrict__ Wt,
                const float* __restrict__ bprep,
                unsigned short* __restrict__ qo,
                unsigned short* __restrict__ ko,
                unsigned short* __restrict__ vt)
{
    const int tid  = threadIdx.x;
    const int wv   = tid >> 6;
    const int lane = tid & 63;
    const int lo   = lane & 15;
    const int quad = lane >> 4;
    const long rowbase = (long)blockIdx.x * 64 + wv * 16;

    // x fragments (A/B operand: row = rowbase+lo, k = ks*32+quad*8)
    bf16x8 xf[4];
    {
        const float4* xr = reinterpret_cast<const float4*>(&x[(rowbase + lo) * C]);
        #pragma unroll
        for (int ks = 0; ks < 4; ++ks) {
            float4 a  = xr[ks * 8 + quad * 2];
            float4 b2 = xr[ks * 8 + quad * 2 + 1];
            union { bf16x8 v; unsigned int u[4]; } cv;
            cv.u[0] = pack2bf(a.x, a.y);
            cv.u[1] = pack2bf(a.z, a.w);
            cv.u[2] = pack2bf(b2.x, b2.y);
            cv.u[3] = pack2bf(b2.z, b2.w);
            xf[ks] = cv.v;
        }
    }

    // ---- q and k: D[m=outchan][n=row], A=Wt, B=xf ----
    #pragma unroll
    for (int mat = 0; mat < 2; ++mat) {
        const unsigned short* Wm = Wt + mat * 16384;
        const float* bm = bprep + mat * 128;
        f32x4 acc[8] = {};
        #pragma unroll
        for (int ks = 0; ks < 4; ++ks)
            #pragma unroll
            for (int mt = 0; mt < 8; ++mt) {
                bf16x8 wf = *reinterpret_cast<const bf16x8*>(
                    &Wm[(mt * 16 + lo) * C + ks * 32 + quad * 8]);
                acc[mt] = __builtin_amdgcn_mfma_f32_16x16x32_bf16(
                    wf, xf[ks], acc[mt], 0, 0, 0);
            }
        unsigned short* out = (mat == 0) ? qo : ko;
        long row = rowbase + lo;
        #pragma unroll
        for (int mt = 0; mt < 8; ++mt) {
            float4 bb = *reinterpret_cast<const float4*>(&bm[mt * 16 + quad * 4]);
            uint2 w;
            w.x = pack2bf(acc[mt][0] + bb.x, acc[mt][1] + bb.y);
            w.y = pack2bf(acc[mt][2] + bb.z, acc[mt][3] + bb.w);
            *reinterpret_cast<uint2*>(&out[row * C + mt * 16 + quad * 4]) = w;
        }
    }

    // ---- v: D[m=row][n=chan], A=xf, B=Wt; store tiled transposed ----
    {
        const unsigned short* Wm = Wt + 2 * 16384;
        const float* bm = bprep + 2 * 128;
        f32x4 acc[8] = {};
        #pragma unroll
        for (int ks = 0; ks < 4; ++ks)
            #pragma unroll
            for (int ct = 0; ct < 8; ++ct) {
                bf16x8 wf = *reinterpret_cast<const bf16x8*>(
                    &Wm[(ct * 16 + lo) * C + ks * 32 + quad * 8]);
                acc[ct] = __builtin_amdgcn_mfma_f32_16x16x32_bf16(
                    xf[ks], wf, acc[ct], 0, 0, 0);
            }
        const int b = (int)(rowbase >> 12);
        const int nbase = (int)(rowbase & (N - 1));
        const int n0   = nbase + quad * 4;
        const int nblk = n0 >> 6;
        #pragma unroll
        for (int ct = 0; ct < 8; ++ct) {
            int chan = ct * 16 + lo;
            float bb = bm[chan];
            uint2 w;
            w.x = pack2bf(acc[ct][0] + bb, acc[ct][1] + bb);
            w.y = pack2bf(acc[ct][2] + bb, acc[ct][3] + bb);
            *reinterpret_cast<uint2*>(
                &vt[(((size_t)b * 64 + nblk) * 128 + chan) * 64 + (n0 & 63)]) = w;
        }
    }
}

// ---------------------------------------------------------------------------
// Flash attention, barrier-free, XCD-swizzled, HIGH OCCUPANCY.
// grid = nspl*256 blocks (1-D), block 256 (4 waves), wave owns 16 q-rows.
// 4 blocks/CU x 4 waves = 16 waves/CU. Decode keeps id%8 == f(batch,
// split-parity): each XCD sees ONE batch, 2 splits -> K/V+Q ~2 MB L2-resident.
// K fragments direct from global; V from tiled vt; P via per-wave LDS
// (C-layout -> A-layout transform); alpha via per-wave LDS broadcast.
// ---------------------------------------------------------------------------
__global__ __launch_bounds__(256, 4)
void attn_kernel(const unsigned short* __restrict__ q,
                 const unsigned short* __restrict__ k,
                 const unsigned short* __restrict__ vt,
                 unsigned short* __restrict__ opart,
                 float2* __restrict__ ml)
{
    __shared__ __align__(16) unsigned short pl[4 * 16 * PSTR];  // 9216 B
    __shared__ float albuf[4][16];

    const int tid  = threadIdx.x;
    const int wv   = tid >> 6;
    const int lane = tid & 63;
    const int lo   = lane & 15;
    const int quad = lane >> 4;

    const int nspl = (int)(gridDim.x >> 8);      // 256 blocks per split-set
    const int id   = blockIdx.x;
    int b, sl, qt;
    if (nspl == 4) {         // id%8 = b*2 + (sl&1)
        b  = (id >> 1) & 3;
        sl = (id & 1) | (((id >> 3) & 1) << 1);
        qt = id >> 4;        // 0..63
    } else {                 // nspl == 2: id%8 = b*2 + sl
        b  = (id >> 1) & 3;
        sl = id & 1;
        qt = id >> 3;        // 0..63
    }
    const int NIT  = (N / nspl) / BK;
    const int koff = sl * (N / nspl);

    const size_t qrow0 = (size_t)b * N + qt * 64 + wv * 16;
    const unsigned short* kb  = k  + ((size_t)b * N + koff) * C;
    const unsigned short* vtb = vt + ((size_t)b * 64 + (koff >> 6)) * (size_t)(128 * 64);
    unsigned short* plw = pl + wv * 16 * PSTR;

    // Q fragments (B operand): row = qrow0 + lo, k = ks*32 + quad*8
    bf16x8 qf[4];
    #pragma unroll
    for (int ks = 0; ks < 4; ++ks)
        qf[ks] = *reinterpret_cast<const bf16x8*>(
            &q[(qrow0 + lo) * C + ks * 32 + quad * 8]);

    float m_i = -1e30f;
    float l_i = 0.f;
    f32x4 ot[8] = {};   // [ct]: rows quad*4+reg, chan ct*16+lo

    for (int kt = 0; kt < NIT; ++kt) {
        const unsigned short* kt_base = kb  + (size_t)kt * BK * C;
        const unsigned short* vt_base = vtb + (size_t)kt * (128 * 64);

        // ---- S^T = K . Q^T : st[mt], key = mt*16+quad*4+reg, qrow = lo ----
        f32x4 st[4] = {};
        #pragma unroll
        for (int ks = 0; ks < 4; ++ks)
            #pragma unroll
            for (int mt = 0; mt < 4; ++mt) {
                bf16x8 kf = *reinterpret_cast<const bf16x8*>(
                    &kt_base[(size_t)(mt * 16 + lo) * C + ks * 32 + quad * 8]);
                st[mt] = __builtin_amdgcn_mfma_f32_16x16x32_bf16(
                    kf, qf[ks], st[mt], 0, 0, 0);
            }

        // ---- online softmax (per lane: col = qrow = lo) ----
        float mx = -1e30f;
        #pragma unroll
        for (int mt = 0; mt < 4; ++mt)
            #pragma unroll
            for (int r = 0; r < 4; ++r)
                mx = fmaxf(mx, st[mt][r]);
        mx = fmaxf(mx, __shfl_xor(mx, 16));
        mx = fmaxf(mx, __shfl_xor(mx, 32));
        float mnew = fmaxf(m_i, mx);
        float al   = __expf(m_i - mnew);
        m_i = mnew;
        float ps = 0.f;
        #pragma unroll
        for (int mt = 0; mt < 4; ++mt) {
            float p0 = __expf(st[mt][0] - mnew);
            float p1 = __expf(st[mt][1] - mnew);
            float p2 = __expf(st[mt][2] - mnew);
            float p3 = __expf(st[mt][3] - mnew);
            ps += (p0 + p1) + (p2 + p3);
            uint2 w;
            w.x = pack2bf(p0, p1);
            w.y = pack2bf(p2, p3);
            *reinterpret_cast<uint2*>(&plw[lo * PSTR + mt * 16 + quad * 4]) = w;
        }
        ps += __shfl_xor(ps, 16);
        ps += __shfl_xor(ps, 32);
        l_i = al * l_i + ps;
        if (quad == 0) albuf[wv][lo] = al;

        // ---- rescale O, then O += P.V ----
        f32x4 al4 = *reinterpret_cast<const f32x4*>(&albuf[wv][quad * 4]);
        #pragma unroll
        for (int ct = 0; ct < 8; ++ct)
            #pragma unroll
            for (int r = 0; r < 4; ++r)
                ot[ct][r] *= al4[r];

        #pragma unroll
        for (int ks2 = 0; ks2 < 2; ++ks2) {
            bf16x8 pf = *reinterpret_cast<const bf16x8*>(
                &plw[lo * PSTR + ks2 * 32 + quad * 8]);
            #pragma unroll
            for (int ct = 0; ct < 8; ++ct) {
                bf16x8 vf = *reinterpret_cast<const bf16x8*>(
                    &vt_base[(ct * 16 + lo) * 64 + ks2 * 32 + quad * 8]);
                ot[ct] = __builtin_amdgcn_mfma_f32_16x16x32_bf16(
                    pf, vf, ot[ct], 0, 0, 0);
            }
        }
    }

    // ---- write partials: unnormalized O (bf16), m/l per row ----
    unsigned short* ob = opart + (size_t)sl * TOTROWS * C;
    #pragma unroll
    for (int r = 0; r < 4; ++r) {
        size_t rowg = qrow0 + quad * 4 + r;
        #pragma unroll
        for (int ct = 0; ct < 8; ++ct)
            ob[rowg * C + ct * 16 + lo] = f2bf(ot[ct][r]);
    }
    if (quad == 0) {
        float2 v; v.x = m_i; v.y = l_i;
        ml[(size_t)sl * TOTROWS + qrow0 + lo] = v;
    }
}

// ---------------------------------------------------------------------------
// Combine nspl splits + residual: out = x + (sum_j w_j O_j) / (sum_j w_j l_j)
// ---------------------------------------------------------------------------
__global__ __launch_bounds__(256)
void combine_kernel(const float* __restrict__ x,
                    const unsigned short* __restrict__ opart,
                    const float2* __restrict__ ml,
                    float* __restrict__ out, int nspl)
{
    int gid = blockIdx.x * 256 + threadIdx.x;     // TOTROWS*32
    int row = gid >> 5;
    int c4  = (gid & 31) * 4;

    float2 mlv[4];
    for (int j = 0; j < nspl; ++j) mlv[j] = ml[(size_t)j * TOTROWS + row];
    float M = mlv[0].x;
    for (int j = 1; j < nspl; ++j) M = fmaxf(M, mlv[j].x);
    float wgt[4]; float denom = 0.f;
    for (int j = 0; j < nspl; ++j) {
        wgt[j] = __expf(mlv[j].x - M);
        denom += mlv[j].y * wgt[j];
    }
    float inv = 1.0f / denom;

    size_t idx = (size_t)row * C + c4;
    float a0 = 0.f, a1 = 0.f, a2 = 0.f, a3 = 0.f;
    for (int j = 0; j < nspl; ++j) {
        uint2 o = *reinterpret_cast<const uint2*>(&opart[(size_t)j * TOTROWS * C + idx]);
        a0 += wgt[j] * bf2f(o.x & 0xffff);
        a1 += wgt[j] * bf2f(o.x >> 16);
        a2 += wgt[j] * bf2f(o.y & 0xffff);
        a3 += wgt[j] * bf2f(o.y >> 16);
    }
    float4 xv = *reinterpret_cast<const float4*>(&x[idx]);
    float4 o;
    o.x = xv.x + a0 * inv;
    o.y = xv.y + a1 * inv;
    o.z = xv.z + a2 * inv;
    o.w = xv.w + a3 * inv;
    *reinterpret_cast<float4*>(&out[idx]) = o;
}

// ---------------------------------------------------------------------------
extern "C" void kernel_launch(void* const* d_in, const int* in_sizes, int n_in,
                              void* d_out, int out_size, void* d_ws, size_t ws_size,
                              hipStream_t stream)
{
    const float* x  = (const float*)d_in[0];
    const float* Wq = (const float*)d_in[1];
    const float* bq = (const float*)d_in[2];
    const float* Wk = (const float*)d_in[3];
    const float* bk = (const float*)d_in[4];
    const float* Wv = (const float*)d_in[5];
    const float* bv = (const float*)d_in[6];
    float* out = (float*)d_out;

    // nspl=4 needs ~28.4 MB of ws; fall back to 2 if the workspace is small.
    const int nspl = (ws_size >= ((size_t)31 << 20)) ? 4 : 2;

    const size_t SPLIT_BYTES = (size_t)TOTROWS * C * 2;   // 4 MB
    char* ws = (char*)d_ws;
    unsigned short* opart = (unsigned short*)ws;                  // nspl*4 MB
    char* base = ws + (size_t)nspl * SPLIT_BYTES;
    unsigned short* q     = (unsigned short*)(base);                      // 4 MB
    unsigned short* k     = (unsigned short*)(base + SPLIT_BYTES);        // 4 MB
    unsigned short* vt    = (unsigned short*)(base + 2 * SPLIT_BYTES);    // 4 MB (tiled)
    unsigned short* Wt    = (unsigned short*)(base + 3 * SPLIT_BYTES);    // 96 KB
    float*          bprep = (float*)(base + 3 * SPLIT_BYTES + 131072);    // 1.5 KB
    float2*         ml    = (float2*)(base + 3 * SPLIT_BYTES + 135168);   // nspl*128 KB

    wprep_kernel<<<3, 256, 0, stream>>>(Wq, bq, Wk, bk, Wv, bv, Wt, bprep);
    qkv_kernel<<<TOTROWS / 64, 256, 0, stream>>>(x, Wt, bprep, q, k, vt);
    attn_kernel<<<nspl * 256, 256, 0, stream>>>(q, k, vt, opart, ml);
    combine_kernel<<<TOTROWS * 32 / 256, 256, 0, stream>>>(x, opart, ml, out, nspl);
}

// Round 7
// 202.832 us; speedup vs baseline: 1.7034x; 1.7034x over previous
//
#include <hip/hip_runtime.h>

// Problem constants: x [4, 64, 64, 128] fp32
constexpr int C       = 128;
constexpr int N       = 4096;
constexpr int BATCH   = 4;
constexpr int TOTROWS = BATCH * N;            // 16384
constexpr float SCALE = 0.08838834764831845f; // 1/sqrt(128)

constexpr int BK   = 64;     // keys per iteration
constexpr int KSTR = 136;    // K-tile LDS stride: 272 B rows -> 2-way banks (free)
constexpr int VSTR = 72;     // V-tile LDS stride: 144 B rows -> 2-way banks
constexpr int PSTR = 72;     // P-tile LDS stride

typedef __attribute__((ext_vector_type(8))) short bf16x8;
typedef __attribute__((ext_vector_type(4))) float f32x4;

__device__ inline unsigned short f2bf(float f) {   // RNE float->bf16
    unsigned int u = __float_as_uint(f);
    return (unsigned short)((u + 0x7FFFu + ((u >> 16) & 1u)) >> 16);
}
__device__ inline unsigned int pack2bf(float a, float b) {
    return (unsigned int)f2bf(a) | ((unsigned int)f2bf(b) << 16);
}
__device__ inline float bf2f(unsigned short u) {
    return __uint_as_float((unsigned int)u << 16);
}

// ---------------------------------------------------------------------------
// wprep: 3 blocks. Coalesced W read -> LDS transpose -> coalesced Wt write.
// Wt[mat][o][i] = W[mat][i][o] (bf16, SCALE folded into mat 0), bias fp32.
// ---------------------------------------------------------------------------
__global__ __launch_bounds__(256)
void wprep_kernel(const float* __restrict__ Wq, const float* __restrict__ bq,
                  const float* __restrict__ Wk, const float* __restrict__ bk,
                  const float* __restrict__ Wv, const float* __restrict__ bv,
                  unsigned short* __restrict__ Wt,
                  float* __restrict__ bprep)
{
    constexpr int TS = 136;
    __shared__ __align__(16) unsigned short wl[128 * TS];
    const int tid = threadIdx.x;
    const int mat = blockIdx.x;
    const float* W = (mat == 0) ? Wq : (mat == 1) ? Wk : Wv;
    const float* b = (mat == 0) ? bq : (mat == 1) ? bk : bv;
    const float s  = (mat == 0) ? SCALE : 1.0f;

    #pragma unroll
    for (int g = 0; g < 16; ++g) {
        int idx = g * 256 + tid;
        int i = idx >> 5, c4 = (idx & 31) * 4;
        float4 a = *reinterpret_cast<const float4*>(&W[i * 128 + c4]);
        wl[(c4 + 0) * TS + i] = f2bf(a.x * s);
        wl[(c4 + 1) * TS + i] = f2bf(a.y * s);
        wl[(c4 + 2) * TS + i] = f2bf(a.z * s);
        wl[(c4 + 3) * TS + i] = f2bf(a.w * s);
    }
    __syncthreads();
    #pragma unroll
    for (int g = 0; g < 8; ++g) {
        int idx = g * 256 + tid;
        int o = idx >> 4, off = (idx & 15) * 8;
        *reinterpret_cast<uint4*>(&Wt[mat * 16384 + o * 128 + off]) =
            *reinterpret_cast<const uint4*>(&wl[o * TS + off]);
    }
    if (tid < 128) bprep[mat * 128 + tid] = b[tid] * s;
}

// ---------------------------------------------------------------------------
// QKV GEMM, pure-register MFMA, one mat per block for occupancy.
// grid (TOTROWS/64, 3) = 768 blocks = 3 blocks/CU. block 256 (4 waves),
// wave owns 16 rows. x read per block (fp32->bf16 in regs); W from L2.
// vt stored TILED: vt[b][n/64][c][n%64].
// ---------------------------------------------------------------------------
__global__ __launch_bounds__(256)
void qkv_kernel(const float* __restrict__ x,
                const unsigned short* __restrict__ Wt,
                const float* __restrict__ bprep,
                unsigned short* __restrict__ qo,
                unsigned short* __restrict__ ko,
                unsigned short* __restrict__ vt)
{
    const int tid  = threadIdx.x;
    const int wv   = tid >> 6;
    const int lane = tid & 63;
    const int lo   = lane & 15;
    const int quad = lane >> 4;
    const int mat  = blockIdx.y;
    const long rowbase = (long)blockIdx.x * 64 + wv * 16;

    const unsigned short* Wm = Wt + mat * 16384;
    const float* bm = bprep + mat * 128;

    // x fragments (row = rowbase+lo, k = ks*32+quad*8), fp32->bf16 in regs
    bf16x8 xf[4];
    {
        const float4* xr = reinterpret_cast<const float4*>(&x[(rowbase + lo) * C]);
        #pragma unroll
        for (int ks = 0; ks < 4; ++ks) {
            float4 a  = xr[ks * 8 + quad * 2];
            float4 b2 = xr[ks * 8 + quad * 2 + 1];
            union { bf16x8 v; unsigned int u[4]; } cv;
            cv.u[0] = pack2bf(a.x, a.y);
            cv.u[1] = pack2bf(a.z, a.w);
            cv.u[2] = pack2bf(b2.x, b2.y);
            cv.u[3] = pack2bf(b2.z, b2.w);
            xf[ks] = cv.v;
        }
    }

    if (mat < 2) {
        // q/k: D[m=outchan][n=row], A=Wt, B=xf -> row-major store
        f32x4 acc[8] = {};
        #pragma unroll
        for (int ks = 0; ks < 4; ++ks)
            #pragma unroll
            for (int mt = 0; mt < 8; ++mt) {
                bf16x8 wf = *reinterpret_cast<const bf16x8*>(
                    &Wm[(mt * 16 + lo) * C + ks * 32 + quad * 8]);
                acc[mt] = __builtin_amdgcn_mfma_f32_16x16x32_bf16(
                    wf, xf[ks], acc[mt], 0, 0, 0);
            }
        unsigned short* out = (mat == 0) ? qo : ko;
        long row = rowbase + lo;
        #pragma unroll
        for (int mt = 0; mt < 8; ++mt) {
            float4 bb = *reinterpret_cast<const float4*>(&bm[mt * 16 + quad * 4]);
            uint2 w;
            w.x = pack2bf(acc[mt][0] + bb.x, acc[mt][1] + bb.y);
            w.y = pack2bf(acc[mt][2] + bb.z, acc[mt][3] + bb.w);
            *reinterpret_cast<uint2*>(&out[row * C + mt * 16 + quad * 4]) = w;
        }
    } else {
        // v: D[m=row][n=chan], A=xf, B=Wt -> tiled transposed store
        f32x4 acc[8] = {};
        #pragma unroll
        for (int ks = 0; ks < 4; ++ks)
            #pragma unroll
            for (int ct = 0; ct < 8; ++ct) {
                bf16x8 wf = *reinterpret_cast<const bf16x8*>(
                    &Wm[(ct * 16 + lo) * C + ks * 32 + quad * 8]);
                acc[ct] = __builtin_amdgcn_mfma_f32_16x16x32_bf16(
                    xf[ks], wf, acc[ct], 0, 0, 0);
            }
        const int b = (int)(rowbase >> 12);
        const int nbase = (int)(rowbase & (N - 1));
        const int n0   = nbase + quad * 4;
        const int nblk = n0 >> 6;
        #pragma unroll
        for (int ct = 0; ct < 8; ++ct) {
            int chan = ct * 16 + lo;
            float bb = bm[chan];
            uint2 w;
            w.x = pack2bf(acc[ct][0] + bb, acc[ct][1] + bb);
            w.y = pack2bf(acc[ct][2] + bb, acc[ct][3] + bb);
            *reinterpret_cast<uint2*>(
                &vt[(((size_t)b * 64 + nblk) * 128 + chan) * 64 + (n0 & 63)]) = w;
        }
    }
}

// ---------------------------------------------------------------------------
// Flash attention, m97-style LDS-staged K-loop + register prefetch.
// grid = nspl*128 blocks, block 256 (4 waves, wave owns 32 q-rows = 128/block).
// 2 blocks/CU co-resident (LDS 54.3 KB) so barrier drains overlap the
// sibling block's compute. XCD swizzle: id%8 pins (batch, split-parity) ->
// K/V+Q working set ~3 MB per XCD, L2-resident. Fragments come from LDS
// (~12cyc b128, 2-way banks free); next tile prefetched into regs right
// after the barrier -> one full iteration of latency slack.
// ---------------------------------------------------------------------------
__global__ __launch_bounds__(256, 2)
void attn_kernel(const unsigned short* __restrict__ q,
                 const unsigned short* __restrict__ k,
                 const unsigned short* __restrict__ vt,
                 unsigned short* __restrict__ opart,
                 float2* __restrict__ ml)
{
    __shared__ __align__(16) unsigned short kl[BK * KSTR];      // 17408 B
    __shared__ __align__(16) unsigned short vl[C * VSTR];       // 18432 B
    __shared__ __align__(16) unsigned short pl[4 * 32 * PSTR];  // 18432 B

    const int tid  = threadIdx.x;
    const int wv   = tid >> 6;
    const int lane = tid & 63;
    const int lo   = lane & 15;
    const int quad = lane >> 4;

    const int nspl = (int)(gridDim.x >> 7);      // 512 -> 4, 256 -> 2
    const int id   = blockIdx.x;
    int b, sl, qt;
    if (nspl == 4) {         // id%8 = b*2 + (sl&1)
        b  = (id >> 1) & 3;
        sl = (id & 1) | (((id >> 3) & 1) << 1);
        qt = id >> 4;        // 0..31
    } else {                 // nspl == 2
        b  = (id >> 1) & 3;
        sl = id & 1;
        qt = id >> 3;        // 0..31
    }
    const int NIT  = (N / nspl) / BK;
    const int koff = sl * (N / nspl);

    const size_t qrow0 = (size_t)b * N + qt * 128 + wv * 32;
    const unsigned short* kb  = k  + ((size_t)b * N + koff) * C;
    const unsigned short* vtb = vt + ((size_t)b * 64 + (koff >> 6)) * (size_t)(128 * 64);
    unsigned short* plw = pl + wv * 32 * PSTR;

    // Q fragments (B operand): qf[nt][ks]: row = qrow0 + nt*16 + lo
    bf16x8 qf[2][4];
    #pragma unroll
    for (int nt = 0; nt < 2; ++nt)
        #pragma unroll
        for (int ks = 0; ks < 4; ++ks)
            qf[nt][ks] = *reinterpret_cast<const bf16x8*>(
                &q[(qrow0 + nt * 16 + lo) * C + ks * 32 + quad * 8]);

    // staging offsets (kt-invariant): thread covers 8 consecutive elems x4
    int gK[4], lK[4], gV[4], lV[4];
    #pragma unroll
    for (int t = 0; t < 4; ++t) {
        int e = t * 2048 + tid * 8;
        gK[t] = e;  lK[t] = (e >> 7) * KSTR + (e & 127);
        gV[t] = e;  lV[t] = (e >> 6) * VSTR + (e & 63);
    }
    // prefetch tile 0 into regs
    uint4 kreg[4], vreg[4];
    #pragma unroll
    for (int t = 0; t < 4; ++t) {
        kreg[t] = *reinterpret_cast<const uint4*>(&kb[gK[t]]);
        vreg[t] = *reinterpret_cast<const uint4*>(&vtb[gV[t]]);
    }

    float m_i[2] = { -1e30f, -1e30f };
    float l_i[2] = { 0.f, 0.f };
    f32x4 ot[2][8] = {};   // [nt][ct]: rows nt*16+quad*4+r, chan ct*16+lo

    for (int kt = 0; kt < NIT; ++kt) {
        __syncthreads();   // all waves done reading kl/vl of prev iter
        #pragma unroll
        for (int t = 0; t < 4; ++t) {
            *reinterpret_cast<uint4*>(&kl[lK[t]]) = kreg[t];
            *reinterpret_cast<uint4*>(&vl[lV[t]]) = vreg[t];
        }
        __syncthreads();
        if (kt + 1 < NIT) {   // prefetch next tile (full iter of slack)
            const unsigned short* kn = kb  + (size_t)(kt + 1) * BK * C;
            const unsigned short* vn = vtb + (size_t)(kt + 1) * (128 * 64);
            #pragma unroll
            for (int t = 0; t < 4; ++t) {
                kreg[t] = *reinterpret_cast<const uint4*>(&kn[gK[t]]);
                vreg[t] = *reinterpret_cast<const uint4*>(&vn[gV[t]]);
            }
        }

        // ---- S^T = K.Q^T : st[mt][nt], key = mt*16+quad*4+r, qrow = nt*16+lo
        f32x4 st[4][2] = {};
        #pragma unroll
        for (int ks = 0; ks < 4; ++ks)
            #pragma unroll
            for (int mt = 0; mt < 4; ++mt) {
                bf16x8 kf = *reinterpret_cast<const bf16x8*>(
                    &kl[(mt * 16 + lo) * KSTR + ks * 32 + quad * 8]);
                #pragma unroll
                for (int nt = 0; nt < 2; ++nt)
                    st[mt][nt] = __builtin_amdgcn_mfma_f32_16x16x32_bf16(
                        kf, qf[nt][ks], st[mt][nt], 0, 0, 0);
            }

        // ---- online softmax (per lane: col = qrow), P -> per-wave LDS ----
        float al[2];
        #pragma unroll
        for (int nt = 0; nt < 2; ++nt) {
            float mx = -1e30f;
            #pragma unroll
            for (int mt = 0; mt < 4; ++mt)
                #pragma unroll
                for (int r = 0; r < 4; ++r)
                    mx = fmaxf(mx, st[mt][nt][r]);
            mx = fmaxf(mx, __shfl_xor(mx, 16));
            mx = fmaxf(mx, __shfl_xor(mx, 32));
            float mnew = fmaxf(m_i[nt], mx);
            al[nt] = __expf(m_i[nt] - mnew);
            m_i[nt] = mnew;
            float ps = 0.f;
            #pragma unroll
            for (int mt = 0; mt < 4; ++mt) {
                float p0 = __expf(st[mt][nt][0] - mnew);
                float p1 = __expf(st[mt][nt][1] - mnew);
                float p2 = __expf(st[mt][nt][2] - mnew);
                float p3 = __expf(st[mt][nt][3] - mnew);
                ps += (p0 + p1) + (p2 + p3);
                uint2 w;
                w.x = pack2bf(p0, p1);
                w.y = pack2bf(p2, p3);
                *reinterpret_cast<uint2*>(
                    &plw[(nt * 16 + lo) * PSTR + mt * 16 + quad * 4]) = w;
            }
            ps += __shfl_xor(ps, 16);
            ps += __shfl_xor(ps, 32);
            l_i[nt] = al[nt] * l_i[nt] + ps;
        }

        // ---- rescale O (alpha via shfl: row j's alpha lives in lane j) ----
        #pragma unroll
        for (int nt = 0; nt < 2; ++nt)
            #pragma unroll
            for (int r = 0; r < 4; ++r) {
                float a = __shfl(al[nt], quad * 4 + r);
                #pragma unroll
                for (int ct = 0; ct < 8; ++ct)
                    ot[nt][ct][r] *= a;
            }

        // ---- O += P.V ----
        #pragma unroll
        for (int ks2 = 0; ks2 < 2; ++ks2) {
            bf16x8 pf[2];
            #pragma unroll
            for (int nt = 0; nt < 2; ++nt)
                pf[nt] = *reinterpret_cast<const bf16x8*>(
                    &plw[(nt * 16 + lo) * PSTR + ks2 * 32 + quad * 8]);
            #pragma unroll
            for (int ct = 0; ct < 8; ++ct) {
                bf16x8 vf = *reinterpret_cast<const bf16x8*>(
                    &vl[(ct * 16 + lo) * VSTR + ks2 * 32 + quad * 8]);
                #pragma unroll
                for (int nt = 0; nt < 2; ++nt)
                    ot[nt][ct] = __builtin_amdgcn_mfma_f32_16x16x32_bf16(
                        pf[nt], vf, ot[nt][ct], 0, 0, 0);
            }
        }
    }

    // ---- write partials: unnormalized O (bf16), m/l per row ----
    unsigned short* ob = opart + (size_t)sl * TOTROWS * C;
    #pragma unroll
    for (int nt = 0; nt < 2; ++nt) {
        #pragma unroll
        for (int r = 0; r < 4; ++r) {
            size_t rowg = qrow0 + nt * 16 + quad * 4 + r;
            #pragma unroll
            for (int ct = 0; ct < 8; ++ct)
                ob[rowg * C + ct * 16 + lo] = f2bf(ot[nt][ct][r]);
        }
        if (quad == 0) {
            float2 v; v.x = m_i[nt]; v.y = l_i[nt];
            ml[(size_t)sl * TOTROWS + qrow0 + nt * 16 + lo] = v;
        }
    }
}

// ---------------------------------------------------------------------------
// Combine nspl splits + residual: out = x + (sum_j w_j O_j) / (sum_j w_j l_j)
// ---------------------------------------------------------------------------
__global__ __launch_bounds__(256)
void combine_kernel(const float* __restrict__ x,
                    const unsigned short* __restrict__ opart,
                    const float2* __restrict__ ml,
                    float* __restrict__ out, int nspl)
{
    int gid = blockIdx.x * 256 + threadIdx.x;     // TOTROWS*32
    int row = gid >> 5;
    int c4  = (gid & 31) * 4;

    float2 mlv[4];
    for (int j = 0; j < nspl; ++j) mlv[j] = ml[(size_t)j * TOTROWS + row];
    float M = mlv[0].x;
    for (int j = 1; j < nspl; ++j) M = fmaxf(M, mlv[j].x);
    float wgt[4]; float denom = 0.f;
    for (int j = 0; j < nspl; ++j) {
        wgt[j] = __expf(mlv[j].x - M);
        denom += mlv[j].y * wgt[j];
    }
    float inv = 1.0f / denom;

    size_t idx = (size_t)row * C + c4;
    float a0 = 0.f, a1 = 0.f, a2 = 0.f, a3 = 0.f;
    for (int j = 0; j < nspl; ++j) {
        uint2 o = *reinterpret_cast<const uint2*>(&opart[(size_t)j * TOTROWS * C + idx]);
        a0 += wgt[j] * bf2f(o.x & 0xffff);
        a1 += wgt[j] * bf2f(o.x >> 16);
        a2 += wgt[j] * bf2f(o.y & 0xffff);
        a3 += wgt[j] * bf2f(o.y >> 16);
    }
    float4 xv = *reinterpret_cast<const float4*>(&x[idx]);
    float4 o;
    o.x = xv.x + a0 * inv;
    o.y = xv.y + a1 * inv;
    o.z = xv.z + a2 * inv;
    o.w = xv.w + a3 * inv;
    *reinterpret_cast<float4*>(&out[idx]) = o;
}

// ---------------------------------------------------------------------------
extern "C" void kernel_launch(void* const* d_in, const int* in_sizes, int n_in,
                              void* d_out, int out_size, void* d_ws, size_t ws_size,
                              hipStream_t stream)
{
    const float* x  = (const float*)d_in[0];
    const float* Wq = (const float*)d_in[1];
    const float* bq = (const float*)d_in[2];
    const float* Wk = (const float*)d_in[3];
    const float* bk = (const float*)d_in[4];
    const float* Wv = (const float*)d_in[5];
    const float* bv = (const float*)d_in[6];
    float* out = (float*)d_out;

    // nspl=4 needs ~30 MB of ws; fall back to 2 if the workspace is small.
    const int nspl = (ws_size >= ((size_t)31 << 20)) ? 4 : 2;

    const size_t SPLIT_BYTES = (size_t)TOTROWS * C * 2;   // 4 MB
    char* ws = (char*)d_ws;
    unsigned short* opart = (unsigned short*)ws;                  // nspl*4 MB
    char* base = ws + (size_t)nspl * SPLIT_BYTES;
    unsigned short* q     = (unsigned short*)(base);                      // 4 MB
    unsigned short* k     = (unsigned short*)(base + SPLIT_BYTES);        // 4 MB
    unsigned short* vt    = (unsigned short*)(base + 2 * SPLIT_BYTES);    // 4 MB (tiled)
    unsigned short* Wt    = (unsigned short*)(base + 3 * SPLIT_BYTES);    // 96 KB
    float*          bprep = (float*)(base + 3 * SPLIT_BYTES + 131072);    // 1.5 KB
    float2*         ml    = (float2*)(base + 3 * SPLIT_BYTES + 135168);   // nspl*128 KB

    wprep_kernel<<<3, 256, 0, stream>>>(Wq, bq, Wk, bk, Wv, bv, Wt, bprep);
    qkv_kernel<<<dim3(TOTROWS / 64, 3), 256, 0, stream>>>(x, Wt, bprep, q, k, vt);
    attn_kernel<<<nspl * 128, 256, 0, stream>>>(q, k, vt, opart, ml);
    combine_kernel<<<TOTROWS * 32 / 256, 256, 0, stream>>>(x, opart, ml, out, nspl);
}